// Round 17
// baseline (245.867 us; speedup 1.0000x reference)
//
#include <hip/hip_runtime.h>
#include <math.h>

typedef __attribute__((ext_vector_type(8))) short bf16x8;
typedef __attribute__((ext_vector_type(4))) float f32x4;
typedef __attribute__((ext_vector_type(4))) short s16x4;
typedef __attribute__((ext_vector_type(4))) int i32x4;

__device__ inline unsigned short f2bf(float x){
  unsigned u = __builtin_bit_cast(unsigned, x);
  u = (u + 0x7FFFu + ((u >> 16) & 1u)) >> 16;
  return (unsigned short)u;
}
__device__ inline float bf2f(unsigned short v){
  return __builtin_bit_cast(float, (unsigned)v << 16);
}
// HW packed bf16 convert (RNE), T12 primitive — no builtin on gfx950, inline asm
__device__ inline unsigned cvtpk(float lo, float hi){
  unsigned r;
  asm("v_cvt_pk_bf16_f32 %0, %1, %2" : "=v"(r) : "v"(lo), "v"(hi));
  return r;
}

__device__ inline void gl16(const void* g, void* l){
  __builtin_amdgcn_global_load_lds(
      (const __attribute__((address_space(1))) unsigned int*)g,
      (__attribute__((address_space(3))) unsigned int*)l, 16, 0, 0);
}

#define KVLEN 4096
#define QLEN  128
#define NH    32
#define NKVH  8
#define HD    128
#define HIDD  4096
#define NSPLIT 4
#define KVCHUNK (KVLEN / NSPLIT)

#define WSWZ(n) ((((unsigned)(n) & 7u) ^ (((unsigned)(n) >> 3) & 7u)) << 4)
#define VSWZ(byte) ((byte) ^ ((((byte) >> 11) & 7u) << 4))

// ---------------- prep: per-batch RoPE tables (double precision, exact) ----------------
__global__ void prep_kernel(const int* __restrict__ pos32,
                            float* __restrict__ costab,
                            float* __restrict__ sintab){
  int tid = threadIdx.x;
  int b = tid >> 6, j = tid & 63;
  bool pos64 = (pos32[2*4095 + 1] == 0);
  long long mpos;
  if (pos64) mpos = ((const long long*)pos32)[(size_t)b*KVLEN + KVLEN - 1];
  else       mpos = (long long)pos32[(size_t)b*KVLEN + KVLEN - 1];
  double inv = pow(10000.0, -((double)j) / 64.0);
  double ang = (double)mpos * inv;
  costab[b*64 + j] = (float)cos(ang);
  sintab[b*64 + j] = (float)sin(ang);
}

// ---------------- prepall: maskpack + kvprep(+RoPE on K) + wprep + A-tiles ----------------
// All global streams are read-once/write-once -> nontemporal (bypass L2 alloc / RFO).
__global__ __launch_bounds__(256) void prepall_kernel(
    const float* __restrict__ Kg, const float* __restrict__ Vg,
    const float* __restrict__ Wq, const float* __restrict__ Wo,
    const float* __restrict__ hidden, const void* __restrict__ mask,
    const float* __restrict__ costab, const float* __restrict__ sintab,
    unsigned short* __restrict__ Kswz, unsigned short* __restrict__ V2,
    unsigned short* __restrict__ WqImg, unsigned short* __restrict__ WoImg,
    unsigned short* __restrict__ A1img,
    unsigned long long* __restrict__ bits){
  __shared__ alignas(16) char tl[16384];
  int bid = blockIdx.x, tid = threadIdx.x;

  if (bid < 2048){
    const unsigned int* m32 = (const unsigned int*)mask;
    unsigned long long det = __ballot((m32[tid & 63] & 0xFFFFFF00u) != 0);
    bool m8 = (det != 0);
#pragma unroll
    for (int it = 0; it < 4; ++it){
      int idx = bid * 1024 + it * 256 + tid;
      bool v = m8 ? (((const unsigned char*)mask)[idx] != 0)
                  : (((const int*)mask)[idx] != 0);
      unsigned long long bal = __ballot(v);
      if ((tid & 63) == 0) bits[idx >> 6] = bal;
    }

  } else if (bid < 4096){
    // ---- kvprep: t = b*512 + kvh*64 + tile ----
    int t = bid - 2048;
    int b = t >> 9;
    const float* kin = Kg + (size_t)t * 8192;
    const float* vin = Vg + (size_t)t * 8192;
    unsigned short* kout = Kswz + (size_t)t * 8192;
    unsigned short* vout = V2   + (size_t)t * 8192;
#pragma unroll
    for (int i = 0; i < 4; ++i){
      int c = tid + 256*i;
      int r = c >> 4, d0 = (c & 15) * 8;
      int dp = d0 ^ 64;
      bool low = d0 < 64;
      f32x4 x0 = __builtin_nontemporal_load((const f32x4*)(kin + r*128 + d0));
      f32x4 x1 = __builtin_nontemporal_load((const f32x4*)(kin + r*128 + d0 + 4));
      f32x4 y0 = __builtin_nontemporal_load((const f32x4*)(kin + r*128 + dp));
      f32x4 y1 = __builtin_nontemporal_load((const f32x4*)(kin + r*128 + dp + 4));
      int j0 = d0 & 63;
      bf16x8 s;
#pragma unroll
      for (int tt = 0; tt < 8; ++tt){
        float cc = costab[b*64 + j0 + tt];
        float ss = sintab[b*64 + j0 + tt];
        float x = (tt < 4) ? x0[tt] : x1[tt-4];
        float y = (tt < 4) ? y0[tt] : y1[tt-4];
        float v = low ? (x*cc + y*ss) : (x*cc - y*ss);
        s[tt] = (short)f2bf(v);
      }
      unsigned o = ((unsigned)(r*256 + d0*2)) ^ (((unsigned)r & 7u) << 4);
      *(bf16x8*)(tl + o) = s;
    }
    __syncthreads();
#pragma unroll
    for (int i = 0; i < 4; ++i)
      __builtin_nontemporal_store(*(const bf16x8*)(tl + tid*16 + i*4096),
                                  (bf16x8*)((char*)kout + tid*16 + i*4096));
    __syncthreads();
#pragma unroll
    for (int i = 0; i < 4; ++i){
      int c = tid + 256*i;
      int r = c >> 4, d0 = (c & 15) * 8;
      f32x4 x0 = __builtin_nontemporal_load((const f32x4*)(vin + r*128 + d0));
      f32x4 x1 = __builtin_nontemporal_load((const f32x4*)(vin + r*128 + d0 + 4));
      int ks2 = r >> 5, lk4 = (r >> 3) & 3, e = r & 7;
#pragma unroll
      for (int tt = 0; tt < 8; ++tt){
        int d = d0 + tt;
        float v = (tt < 4) ? x0[tt] : x1[tt-4];
        unsigned cc = (unsigned)((((d >> 4)*2 + ks2)*4 + lk4)*16 + (d & 15));
        unsigned byte = cc*16u + (unsigned)e*2u;
        *(unsigned short*)(tl + VSWZ(byte)) = f2bf(v);
      }
    }
    __syncthreads();
#pragma unroll
    for (int i = 0; i < 4; ++i)
      __builtin_nontemporal_store(*(const bf16x8*)(tl + tid*16 + i*4096),
                                  (bf16x8*)((char*)vout + tid*16 + i*4096));

  } else {
    int t = bid - 4096;
    if (t < 8192){
      // B-tiles, bn-fast ordering for DRAM page locality
      const float* W = (t < 4096) ? Wq : Wo;
      unsigned short* img = (t < 4096) ? WqImg : WoImg;
      int tt = t & 4095;
      int kt = tt >> 6, bn = tt & 63;
      char* outB = (char*)img + (size_t)(bn*64 + kt) * 8192;
#pragma unroll
      for (int i = 0; i < 2; ++i){
        int c = tid + 256*i;
        int k = c >> 3, n0 = (c & 7) * 8;
        const float* src = W + (size_t)(kt*64 + k) * HIDD + bn*64 + n0;
        f32x4 x0 = __builtin_nontemporal_load((const f32x4*)src);
        f32x4 x1 = __builtin_nontemporal_load((const f32x4*)(src + 4));
#pragma unroll
        for (int e = 0; e < 8; ++e){
          int n = n0 + e;
          float v = (e < 4) ? x0[e] : x1[e-4];
          unsigned off = ((unsigned)(n*128 + k*2)) ^ WSWZ(n);
          *(unsigned short*)(tl + off) = f2bf(v);
        }
      }
      __syncthreads();
#pragma unroll
      for (int i = 0; i < 2; ++i)
        __builtin_nontemporal_store(*(const bf16x8*)(tl + tid*16 + i*4096),
                                    (bf16x8*)(outB + tid*16 + i*4096));
    } else {
      int ta = t - 8192;                 // [0,512)
      int bm = ta >> 6, kt = ta & 63;
      char* outA = (char*)A1img + (size_t)ta * 8192;
#pragma unroll
      for (int i = 0; i < 2; ++i){
        int c = tid + 256*i;
        int m = c >> 3, kc = c & 7;
        const float* src = hidden + (size_t)(bm*64 + m) * HIDD + kt*64 + kc*8;
        f32x4 x0 = __builtin_nontemporal_load((const f32x4*)src);
        f32x4 x1 = __builtin_nontemporal_load((const f32x4*)(src + 4));
        bf16x8 s;
#pragma unroll
        for (int e = 0; e < 4; ++e){ s[e] = (short)f2bf(x0[e]); s[e+4] = (short)f2bf(x1[e]); }
        unsigned off = ((unsigned)(m*128 + kc*16)) ^ (((unsigned)m & 7u) << 4);
        *(bf16x8*)(tl + off) = s;
      }
      __syncthreads();
#pragma unroll
      for (int i = 0; i < 2; ++i)
        __builtin_nontemporal_store(*(const bf16x8*)(tl + tid*16 + i*4096),
                                    (bf16x8*)(outA + tid*16 + i*4096));
    }
  }
}

// ---------------- GEMM: BM=64 BN=64 BK=128, double-buffered (r15-proven) ----------------
template<int EPI>
__global__ __launch_bounds__(256, 2) void gemm_kernel(const unsigned short* __restrict__ Aimg,
                                                      const unsigned short* __restrict__ Bimg,
                                                      void* __restrict__ C_){
  __shared__ alignas(16) char smem[65536];              // 2 x (A 16KB + B 16KB)
  int bid = blockIdx.x;
  int bn = (bid & 7) | ((bid >> 6) << 3);               // same bn -> same XCD
  int bm = (bid >> 3) & 7;
  int tid = threadIdx.x, lane = tid & 63, w = tid >> 6;
  int wm = w >> 1, wn = w & 1;
  int l16 = lane & 15, lk4 = lane >> 4;
  const char* At = (const char*)Aimg + (size_t)(bm*64) * 8192;
  const char* Bt = (const char*)Bimg + (size_t)(bn*64) * 8192;
  f32x4 acc[2][2] = {};

#define GSTAGE(KT2, BUF) do { \
    const char* ga_ = At + (size_t)(KT2)*16384 + w*4096 + lane*16; \
    const char* gb_ = Bt + (size_t)(KT2)*16384 + w*4096 + lane*16; \
    char* la_ = smem + (BUF)*32768 + w*4096; \
    char* lb_ = smem + (BUF)*32768 + 16384 + w*4096; \
    _Pragma("unroll") for (int i_ = 0; i_ < 4; ++i_) gl16(ga_ + i_*1024, la_ + i_*1024); \
    _Pragma("unroll") for (int i_ = 0; i_ < 4; ++i_) gl16(gb_ + i_*1024, lb_ + i_*1024); \
  } while(0)

  GSTAGE(0, 0);

  for (int kt = 0; kt < 32; ++kt){
    asm volatile("s_waitcnt vmcnt(0)" ::: "memory");
    asm volatile("s_waitcnt lgkmcnt(0)" ::: "memory");
    __builtin_amdgcn_s_barrier();
    __builtin_amdgcn_sched_barrier(0);
    if (kt + 1 < 32) GSTAGE(kt + 1, (kt + 1) & 1);
    const char* Ab = smem + (kt & 1)*32768;
    const char* Bb = Ab + 16384;
    bf16x8 af[2][4], bfr[2][4];
#pragma unroll
    for (int i = 0; i < 2; ++i)
#pragma unroll
      for (int ks = 0; ks < 4; ++ks){
        unsigned m = (unsigned)(wm*32 + i*16 + l16);
        unsigned off = (unsigned)(ks >> 1)*8192u +
                       ((m*128u + (unsigned)((ks & 1)*64 + lk4*16)) ^ ((m & 7u) << 4));
        af[i][ks] = *(const bf16x8*)(Ab + off);
      }
#pragma unroll
    for (int j = 0; j < 2; ++j)
#pragma unroll
      for (int ks = 0; ks < 4; ++ks){
        unsigned n = (unsigned)(wn*32 + j*16 + l16);
        unsigned off = (unsigned)(ks >> 1)*8192u +
                       ((n*128u + (unsigned)((ks & 1)*64 + lk4*16)) ^ WSWZ(n));
        bfr[j][ks] = *(const bf16x8*)(Bb + off);
      }
#pragma unroll
    for (int i = 0; i < 2; ++i)
#pragma unroll
      for (int j = 0; j < 2; ++j)
#pragma unroll
        for (int ks = 0; ks < 4; ++ks)
          acc[i][j] = __builtin_amdgcn_mfma_f32_16x16x32_bf16(af[i][ks], bfr[j][ks], acc[i][j], 0, 0, 0);
  }
#undef GSTAGE

  if (EPI == 0){
    float* C = (float*)C_;
#pragma unroll
    for (int i = 0; i < 2; ++i)
#pragma unroll
      for (int j = 0; j < 2; ++j)
#pragma unroll
        for (int r = 0; r < 4; ++r){
          int row = bm*64 + wm*32 + i*16 + lk4*4 + r;
          int col = bn*64 + wn*32 + j*16 + l16;
          C[(size_t)row * HIDD + col] = acc[i][j][r];
        }
  } else {
    unsigned short* Q = (unsigned short*)C_;
    const float scale = 0.08838834764831845f * 1.4426950408889634f;  // 1/sqrt(D) * log2(e)
#pragma unroll
    for (int i = 0; i < 2; ++i)
#pragma unroll
      for (int j = 0; j < 2; ++j)
#pragma unroll
        for (int r = 0; r < 4; ++r){
          int row = bm*64 + wm*32 + i*16 + lk4*4 + r;
          int col = bn*64 + wn*32 + j*16 + l16;
          int b = row >> 7, ql = row & 127;
          int h = col >> 7, d = col & 127;
          Q[(((size_t)(b*NH + h)) * QLEN + ql) * HD + d] = f2bf(acc[i][j][r] * scale);
        }
  }
}

// ---------------- flash attention: 4-wave blocks, 1 head, qg=2, NSPLIT=4, grid 512 ----
__global__ __launch_bounds__(256, 2) void attn_kernel(const unsigned short* __restrict__ Q,
                                                      const unsigned short* __restrict__ Kswz,
                                                      const unsigned short* __restrict__ V2,
                                                      const unsigned long long* __restrict__ bits,
                                                      unsigned short* __restrict__ Opart,
                                                      float* __restrict__ Mpart,
                                                      float* __restrict__ Lpart){
  __shared__ alignas(16) unsigned short Kbuf[2][8192];
  __shared__ alignas(16) unsigned short Vbuf[2][8192];
  int bid = blockIdx.x;
  int j = (bid >> 3) & 3;
  int g = (bid & 7) | ((bid >> 5) << 3);
  int s   = g & 3;
  int kvh = (g >> 2) & 7;
  int b   = g >> 5;
  int h   = kvh * 4 + j;

  int tid = threadIdx.x, lane = tid & 63, w = tid >> 6;
  int l16 = lane & 15, lk4 = lane >> 4;
  int lk4x4 = lk4 * 4;

  bf16x8 qf[2][4];
#pragma unroll
  for (int qg = 0; qg < 2; ++qg){
    const unsigned short* qp = Q + (((size_t)(b*NH + h) * QLEN) + w*32 + qg*16 + l16) * HD;
#pragma unroll
    for (int ks = 0; ks < 4; ++ks)
      qf[qg][ks] = *(const bf16x8*)(qp + ks*32 + lk4*8);
  }
  bf16x8 vone;
#pragma unroll
  for (int t = 0; t < 8; ++t) vone[t] = (short)0x3F80;

  f32x4 acc_o[2][8] = {};
  f32x4 acc_l[2] = {};
  float mrun[2] = {-1e30f, -1e30f};

  size_t kvhbase = (size_t)(b*NKVH + kvh) * (KVLEN/64);
  const unsigned short* Ktiles = Kswz + kvhbase * 8192;
  const unsigned short* Vtiles = V2   + kvhbase * 8192;
  size_t qrow0 = (size_t)(b*QLEN + w*32 + l16);

  const int t0 = s * (KVCHUNK/64), t1 = t0 + KVCHUNK/64;
  int srcb0 = (l16 + ((lk4 & 1) << 5)) << 2;
  int srcb1 = srcb0 + 64;

#define STAGE(T, BUF) do { \
    const char* gk_ = (const char*)(Ktiles + (size_t)(T)*8192) + w*4096 + lane*16; \
    const char* gv_ = (const char*)(Vtiles + (size_t)(T)*8192) + w*4096 + lane*16; \
    char* lk_ = (char*)(&Kbuf[BUF][0]) + w*4096; \
    char* lv_ = (char*)(&Vbuf[BUF][0]) + w*4096; \
    _Pragma("unroll") for (int i_ = 0; i_ < 4; ++i_) gl16(gk_ + i_*1024, lk_ + i_*1024); \
    _Pragma("unroll") for (int i_ = 0; i_ < 4; ++i_) gl16(gv_ + i_*1024, lv_ + i_*1024); \
  } while(0)

  STAGE(t0, 0);
  int cur = 0;
  for (int t = t0; t < t1; ++t){
    asm volatile("s_waitcnt vmcnt(0)" ::: "memory");
    asm volatile("s_waitcnt lgkmcnt(0)" ::: "memory");
    __builtin_amdgcn_s_barrier();
    __builtin_amdgcn_sched_barrier(0);
    if (t + 1 < t1) STAGE(t + 1, cur ^ 1);

    unsigned long long wrd[2];
    wrd[0] = bits[qrow0*64 + (size_t)t];
    wrd[1] = bits[(qrow0 + 16)*64 + (size_t)t];

    const char* Kc = (const char*)&Kbuf[cur][0];
    const char* Vc = (const char*)&Vbuf[cur][0];

    f32x4 sacc[2][4] = {};
#pragma unroll
    for (int nf = 0; nf < 4; ++nf){
      int krow = nf*16 + l16;
#pragma unroll
      for (int ks = 0; ks < 4; ++ks){
        unsigned byteoff = ((unsigned)krow*256u + (unsigned)(ks*32 + lk4*8)*2u) ^ (((unsigned)krow & 7u) << 4);
        bf16x8 kf = *(const bf16x8*)(Kc + byteoff);
        sacc[0][nf] = __builtin_amdgcn_mfma_f32_16x16x32_bf16(kf, qf[0][ks], sacc[0][nf], 0, 0, 0);
        sacc[1][nf] = __builtin_amdgcn_mfma_f32_16x16x32_bf16(kf, qf[1][ks], sacc[1][nf], 0, 0, 0);
      }
    }

    unsigned P32[2][8];
#pragma unroll
    for (int qg = 0; qg < 2; ++qg){
      float pp[4][4];
      float pm = -1e30f;
#pragma unroll
      for (int nf = 0; nf < 4; ++nf)
#pragma unroll
        for (int r = 0; r < 4; ++r){
          bool mk = (wrd[qg] >> (nf*16 + lk4x4 + r)) & 1ull;
          float sv = mk ? -20000.f : sacc[qg][nf][r];
          pp[nf][r] = sv;
          pm = fmaxf(pm, sv);
        }
      pm = fmaxf(pm, __shfl_xor(pm, 16, 64));
      pm = fmaxf(pm, __shfl_xor(pm, 32, 64));
      if (__any(pm > mrun[qg])){
        float mnew = fmaxf(mrun[qg], pm);
        float corr = exp2f(mrun[qg] - mnew);
        mrun[qg] = mnew;
#pragma unroll
        for (int nf8 = 0; nf8 < 8; ++nf8)
#pragma unroll
          for (int r = 0; r < 4; ++r) acc_o[qg][nf8][r] *= corr;
#pragma unroll
        for (int r = 0; r < 4; ++r) acc_l[qg][r] *= corr;
      }
#pragma unroll
      for (int nf = 0; nf < 4; ++nf){
        float e0 = exp2f(pp[nf][0] - mrun[qg]);
        float e1 = exp2f(pp[nf][1] - mrun[qg]);
        float e2 = exp2f(pp[nf][2] - mrun[qg]);
        float e3 = exp2f(pp[nf][3] - mrun[qg]);
        P32[qg][nf*2]     = cvtpk(e0, e1);
        P32[qg][nf*2 + 1] = cvtpk(e2, e3);
      }
    }

    bf16x8 pf[2][2];
    bool hi = lk4 >= 2;
#pragma unroll
    for (int qg = 0; qg < 2; ++qg)
#pragma unroll
      for (int ks2 = 0; ks2 < 2; ++ks2){
        int a0 = __builtin_amdgcn_ds_bpermute(srcb0, (int)P32[qg][ks2*4 + 0]);
        int b0 = __builtin_amdgcn_ds_bpermute(srcb0, (int)P32[qg][ks2*4 + 2]);
        int a1 = __builtin_amdgcn_ds_bpermute(srcb0, (int)P32[qg][ks2*4 + 1]);
        int b1 = __builtin_amdgcn_ds_bpermute(srcb0, (int)P32[qg][ks2*4 + 3]);
        int a2 = __builtin_amdgcn_ds_bpermute(srcb1, (int)P32[qg][ks2*4 + 0]);
        int b2 = __builtin_amdgcn_ds_bpermute(srcb1, (int)P32[qg][ks2*4 + 2]);
        int a3 = __builtin_amdgcn_ds_bpermute(srcb1, (int)P32[qg][ks2*4 + 1]);
        int b3 = __builtin_amdgcn_ds_bpermute(srcb1, (int)P32[qg][ks2*4 + 3]);
        i32x4 wv = { hi ? b0 : a0, hi ? b1 : a1, hi ? b2 : a2, hi ? b3 : a3 };
        pf[qg][ks2] = __builtin_bit_cast(bf16x8, wv);
      }

#pragma unroll
    for (int nf8 = 0; nf8 < 8; ++nf8)
#pragma unroll
      for (int ks2 = 0; ks2 < 2; ++ks2){
        unsigned base = (unsigned)(nf8*2 + ks2)*1024u + (unsigned)lane*16u;
        unsigned byteoff = VSWZ(base);
        bf16x8 vf = *(const bf16x8*)(Vc + byteoff);
        acc_o[0][nf8] = __builtin_amdgcn_mfma_f32_16x16x32_bf16(vf, pf[0][ks2], acc_o[0][nf8], 0, 0, 0);
        acc_o[1][nf8] = __builtin_amdgcn_mfma_f32_16x16x32_bf16(vf, pf[1][ks2], acc_o[1][nf8], 0, 0, 0);
      }
#pragma unroll
    for (int qg = 0; qg < 2; ++qg)
#pragma unroll
      for (int ks2 = 0; ks2 < 2; ++ks2)
        acc_l[qg] = __builtin_amdgcn_mfma_f32_16x16x32_bf16(vone, pf[qg][ks2], acc_l[qg], 0, 0, 0);

    cur ^= 1;
  }
#undef STAGE

  size_t rowbase = ((size_t)(s*4 + b) * NH + h) * QLEN + w*32 + l16;
#pragma unroll
  for (int qg = 0; qg < 2; ++qg){
    size_t row = rowbase + qg*16;
#pragma unroll
    for (int nf8 = 0; nf8 < 8; ++nf8){
      s16x4 o;
#pragma unroll
      for (int r = 0; r < 4; ++r) o[r] = (short)f2bf(acc_o[qg][nf8][r]);
      *(s16x4*)&Opart[row * HD + nf8*16 + lk4x4] = o;
    }
    if (lk4 == 0){
      Mpart[row] = mrun[qg];
      Lpart[row] = acc_l[qg][0];
    }
  }
}

// ---------------- combine: merge NSPLIT bf16 partials -> bf16 A-image for GEMM2 ----------------
__global__ __launch_bounds__(256) void combine_kernel(const unsigned short* __restrict__ Opart,
                                                      const float* __restrict__ Mpart,
                                                      const float* __restrict__ Lpart,
                                                      unsigned short* __restrict__ A2img){
  int idx = blockIdx.x * 256 + threadIdx.x;
  int d4 = idx & 31;
  int row = idx >> 5;
  const int RS = 4 * NH * QLEN;
  float m[NSPLIT];
  float M = -1e30f;
#pragma unroll
  for (int s = 0; s < NSPLIT; ++s){
    m[s] = Mpart[(size_t)s*RS + row];
    M = fmaxf(M, m[s]);
  }
  float L = 0.f;
  f32x4 num = {};
#pragma unroll
  for (int s = 0; s < NSPLIT; ++s){
    float wsc = exp2f(m[s] - M);
    L += wsc * Lpart[(size_t)s*RS + row];
    s16x4 o = *(const s16x4*)&Opart[((size_t)s*RS + row) * HD + d4*4];
#pragma unroll
    for (int t = 0; t < 4; ++t) num[t] += wsc * bf2f((unsigned short)o[t]);
  }
  int ql = row & 127, h = (row >> 7) & 31, b = row >> 12;
  int bm = b*2 + (ql >> 6), mm = ql & 63;
  int kt = h*2 + (d4 >> 4), kl = (d4*4) & 63;
  s16x4 res;
#pragma unroll
  for (int t = 0; t < 4; ++t) res[t] = (short)f2bf(num[t] / L);
  char* tile = (char*)A2img + (size_t)(bm*64 + kt) * 8192;
  unsigned off = ((unsigned)(mm*128 + kl*2)) ^ (((unsigned)mm & 7u) << 4);
  *(s16x4*)(tile + off) = res;
}

// ---------------- launch ----------------
extern "C" void kernel_launch(void* const* d_in, const int* in_sizes, int n_in,
                              void* d_out, int out_size, void* d_ws, size_t ws_size,
                              hipStream_t stream){
  (void)in_sizes; (void)n_in; (void)out_size; (void)ws_size;
  const float* hidden = (const float*)d_in[0];
  const float* kst    = (const float*)d_in[1];
  const float* vst    = (const float*)d_in[2];
  const float* wq     = (const float*)d_in[3];
  const float* wo     = (const float*)d_in[4];
  const void*  pos    = d_in[5];
  const void*  mask   = d_in[6];
  float* out = (float*)d_out;

  char* ws = (char*)d_ws;
  unsigned short* Kswz  = (unsigned short*)ws;                   // 32 MiB
  unsigned short* V2    = (unsigned short*)(ws + (32u << 20));   // 32 MiB
  unsigned short* WoImg = (unsigned short*)(ws + (64u << 20));   // 32 MiB
  unsigned short* WqImg = (unsigned short*)(ws + (96u << 20));   // 32 MiB (dead after GEMM1)
  unsigned short* Opart = (unsigned short*)(ws + (96u << 20));   // 16 MiB overlay on WqImg
  unsigned short* A1img = (unsigned short*)(ws + (128u << 20));  // 4 MiB
  unsigned short* qbf   = (unsigned short*)(ws + (132u << 20));  // 4 MiB
  unsigned short* A2img = (unsigned short*)(ws + (136u << 20));  // 4 MiB
  float* Mpart = (float*)(ws + (140u << 20));                    // 256 KiB
  float* Lpart = (float*)(ws + (140u << 20) + (256u << 10));     // 256 KiB
  unsigned long long* bits = (unsigned long long*)(ws + (140u << 20) + (512u << 10)); // 256 KiB
  float* costab = (float*)(ws + (141u << 20));
  float* sintab = costab + 256;

  prep_kernel<<<1, 256, 0, stream>>>((const int*)pos, costab, sintab);
  prepall_kernel<<<12800, 256, 0, stream>>>(kst, vst, wq, wo, hidden, mask,
                                            costab, sintab,
                                            Kswz, V2, WqImg, WoImg, A1img, bits);
  gemm_kernel<1><<<512, 256, 0, stream>>>(A1img, WqImg, qbf);
  attn_kernel<<<512, 256, 0, stream>>>(qbf, Kswz, V2, bits, Opart, Mpart, Lpart);
  combine_kernel<<<2048, 256, 0, stream>>>(Opart, Mpart, Lpart, A2img);
  gemm_kernel<0><<<512, 256, 0, stream>>>(A2img, WoImg, out);
}

// Round 18
// 218.487 us; speedup vs baseline: 1.1253x; 1.1253x over previous
//
#include <hip/hip_runtime.h>
#include <math.h>

typedef __attribute__((ext_vector_type(8))) short bf16x8;
typedef __attribute__((ext_vector_type(4))) float f32x4;
typedef __attribute__((ext_vector_type(4))) short s16x4;
typedef __attribute__((ext_vector_type(4))) int i32x4;

__device__ inline unsigned short f2bf(float x){
  unsigned u = __builtin_bit_cast(unsigned, x);
  u = (u + 0x7FFFu + ((u >> 16) & 1u)) >> 16;
  return (unsigned short)u;
}
__device__ inline float bf2f(unsigned short v){
  return __builtin_bit_cast(float, (unsigned)v << 16);
}
__device__ inline unsigned pk2bf(float lo, float hi){
  return (unsigned)f2bf(lo) | ((unsigned)f2bf(hi) << 16);
}

__device__ inline void gl16(const void* g, void* l){
  __builtin_amdgcn_global_load_lds(
      (const __attribute__((address_space(1))) unsigned int*)g,
      (__attribute__((address_space(3))) unsigned int*)l, 16, 0, 0);
}

#define KVLEN 4096
#define QLEN  128
#define NH    32
#define NKVH  8
#define HD    128
#define HIDD  4096
#define NSPLIT 4
#define KVCHUNK (KVLEN / NSPLIT)

#define WSWZ(n) ((((unsigned)(n) & 7u) ^ (((unsigned)(n) >> 3) & 7u)) << 4)
#define VSWZ(byte) ((byte) ^ ((((byte) >> 11) & 7u) << 4))

// ---------------- prep: per-batch RoPE tables (double precision, exact) ----------------
__global__ void prep_kernel(const int* __restrict__ pos32,
                            float* __restrict__ costab,
                            float* __restrict__ sintab){
  int tid = threadIdx.x;
  int b = tid >> 6, j = tid & 63;
  bool pos64 = (pos32[2*4095 + 1] == 0);
  long long mpos;
  if (pos64) mpos = ((const long long*)pos32)[(size_t)b*KVLEN + KVLEN - 1];
  else       mpos = (long long)pos32[(size_t)b*KVLEN + KVLEN - 1];
  double inv = pow(10000.0, -((double)j) / 64.0);
  double ang = (double)mpos * inv;
  costab[b*64 + j] = (float)cos(ang);
  sintab[b*64 + j] = (float)sin(ang);
}

// ---------------- prepall: maskpack + kvprep(+RoPE on K) + wprep + A-tiles ----------------
// nt LOADS only (read-once fp32 inputs, keep L2 for the images).
// Image STORES are normal: attn/GEMM read them next (r17 lesson: nt stores cost +38us).
__global__ __launch_bounds__(256) void prepall_kernel(
    const float* __restrict__ Kg, const float* __restrict__ Vg,
    const float* __restrict__ Wq, const float* __restrict__ Wo,
    const float* __restrict__ hidden, const void* __restrict__ mask,
    const float* __restrict__ costab, const float* __restrict__ sintab,
    unsigned short* __restrict__ Kswz, unsigned short* __restrict__ V2,
    unsigned short* __restrict__ WqImg, unsigned short* __restrict__ WoImg,
    unsigned short* __restrict__ A1img,
    unsigned long long* __restrict__ bits){
  __shared__ alignas(16) char tl[16384];
  int bid = blockIdx.x, tid = threadIdx.x;

  if (bid < 2048){
    const unsigned int* m32 = (const unsigned int*)mask;
    unsigned long long det = __ballot((m32[tid & 63] & 0xFFFFFF00u) != 0);
    bool m8 = (det != 0);
#pragma unroll
    for (int it = 0; it < 4; ++it){
      int idx = bid * 1024 + it * 256 + tid;
      bool v = m8 ? (((const unsigned char*)mask)[idx] != 0)
                  : (((const int*)mask)[idx] != 0);
      unsigned long long bal = __ballot(v);
      if ((tid & 63) == 0) bits[idx >> 6] = bal;
    }

  } else if (bid < 4096){
    // ---- kvprep: t = b*512 + kvh*64 + tile ----
    int t = bid - 2048;
    int b = t >> 9;
    const float* kin = Kg + (size_t)t * 8192;
    const float* vin = Vg + (size_t)t * 8192;
    unsigned short* kout = Kswz + (size_t)t * 8192;
    unsigned short* vout = V2   + (size_t)t * 8192;
#pragma unroll
    for (int i = 0; i < 4; ++i){
      int c = tid + 256*i;
      int r = c >> 4, d0 = (c & 15) * 8;
      int dp = d0 ^ 64;
      bool low = d0 < 64;
      f32x4 x0 = __builtin_nontemporal_load((const f32x4*)(kin + r*128 + d0));
      f32x4 x1 = __builtin_nontemporal_load((const f32x4*)(kin + r*128 + d0 + 4));
      f32x4 y0 = __builtin_nontemporal_load((const f32x4*)(kin + r*128 + dp));
      f32x4 y1 = __builtin_nontemporal_load((const f32x4*)(kin + r*128 + dp + 4));
      int j0 = d0 & 63;
      bf16x8 s;
#pragma unroll
      for (int tt = 0; tt < 8; ++tt){
        float cc = costab[b*64 + j0 + tt];
        float ss = sintab[b*64 + j0 + tt];
        float x = (tt < 4) ? x0[tt] : x1[tt-4];
        float y = (tt < 4) ? y0[tt] : y1[tt-4];
        float v = low ? (x*cc + y*ss) : (x*cc - y*ss);
        s[tt] = (short)f2bf(v);
      }
      unsigned o = ((unsigned)(r*256 + d0*2)) ^ (((unsigned)r & 7u) << 4);
      *(bf16x8*)(tl + o) = s;
    }
    __syncthreads();
#pragma unroll
    for (int i = 0; i < 4; ++i)
      *(bf16x8*)((char*)kout + tid*16 + i*4096) = *(const bf16x8*)(tl + tid*16 + i*4096);
    __syncthreads();
#pragma unroll
    for (int i = 0; i < 4; ++i){
      int c = tid + 256*i;
      int r = c >> 4, d0 = (c & 15) * 8;
      f32x4 x0 = __builtin_nontemporal_load((const f32x4*)(vin + r*128 + d0));
      f32x4 x1 = __builtin_nontemporal_load((const f32x4*)(vin + r*128 + d0 + 4));
      int ks2 = r >> 5, lk4 = (r >> 3) & 3, e = r & 7;
#pragma unroll
      for (int tt = 0; tt < 8; ++tt){
        int d = d0 + tt;
        float v = (tt < 4) ? x0[tt] : x1[tt-4];
        unsigned cc = (unsigned)((((d >> 4)*2 + ks2)*4 + lk4)*16 + (d & 15));
        unsigned byte = cc*16u + (unsigned)e*2u;
        *(unsigned short*)(tl + VSWZ(byte)) = f2bf(v);
      }
    }
    __syncthreads();
#pragma unroll
    for (int i = 0; i < 4; ++i)
      *(bf16x8*)((char*)vout + tid*16 + i*4096) = *(const bf16x8*)(tl + tid*16 + i*4096);

  } else {
    int t = bid - 4096;
    if (t < 8192){
      // B-tiles, bn-fast ordering for DRAM page locality
      const float* W = (t < 4096) ? Wq : Wo;
      unsigned short* img = (t < 4096) ? WqImg : WoImg;
      int tt = t & 4095;
      int kt = tt >> 6, bn = tt & 63;
      char* outB = (char*)img + (size_t)(bn*64 + kt) * 8192;
#pragma unroll
      for (int i = 0; i < 2; ++i){
        int c = tid + 256*i;
        int k = c >> 3, n0 = (c & 7) * 8;
        const float* src = W + (size_t)(kt*64 + k) * HIDD + bn*64 + n0;
        f32x4 x0 = __builtin_nontemporal_load((const f32x4*)src);
        f32x4 x1 = __builtin_nontemporal_load((const f32x4*)(src + 4));
#pragma unroll
        for (int e = 0; e < 8; ++e){
          int n = n0 + e;
          float v = (e < 4) ? x0[e] : x1[e-4];
          unsigned off = ((unsigned)(n*128 + k*2)) ^ WSWZ(n);
          *(unsigned short*)(tl + off) = f2bf(v);
        }
      }
      __syncthreads();
#pragma unroll
      for (int i = 0; i < 2; ++i)
        *(bf16x8*)(outB + tid*16 + i*4096) = *(const bf16x8*)(tl + tid*16 + i*4096);
    } else {
      int ta = t - 8192;                 // [0,512)
      int bm = ta >> 6, kt = ta & 63;
      char* outA = (char*)A1img + (size_t)ta * 8192;
#pragma unroll
      for (int i = 0; i < 2; ++i){
        int c = tid + 256*i;
        int m = c >> 3, kc = c & 7;
        const float* src = hidden + (size_t)(bm*64 + m) * HIDD + kt*64 + kc*8;
        f32x4 x0 = __builtin_nontemporal_load((const f32x4*)src);
        f32x4 x1 = __builtin_nontemporal_load((const f32x4*)(src + 4));
        bf16x8 s;
#pragma unroll
        for (int e = 0; e < 4; ++e){ s[e] = (short)f2bf(x0[e]); s[e+4] = (short)f2bf(x1[e]); }
        unsigned off = ((unsigned)(m*128 + kc*16)) ^ (((unsigned)m & 7u) << 4);
        *(bf16x8*)(tl + off) = s;
      }
      __syncthreads();
#pragma unroll
      for (int i = 0; i < 2; ++i)
        *(bf16x8*)(outA + tid*16 + i*4096) = *(const bf16x8*)(tl + tid*16 + i*4096);
    }
  }
}

// ---------------- GEMM: BM=64 BN=64 BK=128, double-buffered (r15-proven) ----------------
template<int EPI>
__global__ __launch_bounds__(256, 2) void gemm_kernel(const unsigned short* __restrict__ Aimg,
                                                      const unsigned short* __restrict__ Bimg,
                                                      void* __restrict__ C_){
  __shared__ alignas(16) char smem[65536];              // 2 x (A 16KB + B 16KB)
  int bid = blockIdx.x;
  int bn = (bid & 7) | ((bid >> 6) << 3);               // same bn -> same XCD
  int bm = (bid >> 3) & 7;
  int tid = threadIdx.x, lane = tid & 63, w = tid >> 6;
  int wm = w >> 1, wn = w & 1;
  int l16 = lane & 15, lk4 = lane >> 4;
  const char* At = (const char*)Aimg + (size_t)(bm*64) * 8192;
  const char* Bt = (const char*)Bimg + (size_t)(bn*64) * 8192;
  f32x4 acc[2][2] = {};

#define GSTAGE(KT2, BUF) do { \
    const char* ga_ = At + (size_t)(KT2)*16384 + w*4096 + lane*16; \
    const char* gb_ = Bt + (size_t)(KT2)*16384 + w*4096 + lane*16; \
    char* la_ = smem + (BUF)*32768 + w*4096; \
    char* lb_ = smem + (BUF)*32768 + 16384 + w*4096; \
    _Pragma("unroll") for (int i_ = 0; i_ < 4; ++i_) gl16(ga_ + i_*1024, la_ + i_*1024); \
    _Pragma("unroll") for (int i_ = 0; i_ < 4; ++i_) gl16(gb_ + i_*1024, lb_ + i_*1024); \
  } while(0)

  GSTAGE(0, 0);

  for (int kt = 0; kt < 32; ++kt){
    asm volatile("s_waitcnt vmcnt(0)" ::: "memory");
    asm volatile("s_waitcnt lgkmcnt(0)" ::: "memory");
    __builtin_amdgcn_s_barrier();
    __builtin_amdgcn_sched_barrier(0);
    if (kt + 1 < 32) GSTAGE(kt + 1, (kt + 1) & 1);
    const char* Ab = smem + (kt & 1)*32768;
    const char* Bb = Ab + 16384;
    bf16x8 af[2][4], bfr[2][4];
#pragma unroll
    for (int i = 0; i < 2; ++i)
#pragma unroll
      for (int ks = 0; ks < 4; ++ks){
        unsigned m = (unsigned)(wm*32 + i*16 + l16);
        unsigned off = (unsigned)(ks >> 1)*8192u +
                       ((m*128u + (unsigned)((ks & 1)*64 + lk4*16)) ^ ((m & 7u) << 4));
        af[i][ks] = *(const bf16x8*)(Ab + off);
      }
#pragma unroll
    for (int j = 0; j < 2; ++j)
#pragma unroll
      for (int ks = 0; ks < 4; ++ks){
        unsigned n = (unsigned)(wn*32 + j*16 + l16);
        unsigned off = (unsigned)(ks >> 1)*8192u +
                       ((n*128u + (unsigned)((ks & 1)*64 + lk4*16)) ^ WSWZ(n));
        bfr[j][ks] = *(const bf16x8*)(Bb + off);
      }
#pragma unroll
    for (int i = 0; i < 2; ++i)
#pragma unroll
      for (int j = 0; j < 2; ++j)
#pragma unroll
        for (int ks = 0; ks < 4; ++ks)
          acc[i][j] = __builtin_amdgcn_mfma_f32_16x16x32_bf16(af[i][ks], bfr[j][ks], acc[i][j], 0, 0, 0);
  }
#undef GSTAGE

  if (EPI == 0){
    float* C = (float*)C_;
#pragma unroll
    for (int i = 0; i < 2; ++i)
#pragma unroll
      for (int j = 0; j < 2; ++j)
#pragma unroll
        for (int r = 0; r < 4; ++r){
          int row = bm*64 + wm*32 + i*16 + lk4*4 + r;
          int col = bn*64 + wn*32 + j*16 + l16;
          C[(size_t)row * HIDD + col] = acc[i][j][r];
        }
  } else {
    unsigned short* Q = (unsigned short*)C_;
    const float scale = 0.08838834764831845f * 1.4426950408889634f;  // 1/sqrt(D) * log2(e)
#pragma unroll
    for (int i = 0; i < 2; ++i)
#pragma unroll
      for (int j = 0; j < 2; ++j)
#pragma unroll
        for (int r = 0; r < 4; ++r){
          int row = bm*64 + wm*32 + i*16 + lk4*4 + r;
          int col = bn*64 + wn*32 + j*16 + l16;
          int b = row >> 7, ql = row & 127;
          int h = col >> 7, d = col & 127;
          Q[(((size_t)(b*NH + h)) * QLEN + ql) * HD + d] = f2bf(acc[i][j][r] * scale);
        }
  }
}

// ---------------- flash attention: 4-wave blocks, 1 head, qg=2, NSPLIT=4, grid 512 ----
__global__ __launch_bounds__(256, 2) void attn_kernel(const unsigned short* __restrict__ Q,
                                                      const unsigned short* __restrict__ Kswz,
                                                      const unsigned short* __restrict__ V2,
                                                      const unsigned long long* __restrict__ bits,
                                                      unsigned short* __restrict__ Opart,
                                                      float* __restrict__ Mpart,
                                                      float* __restrict__ Lpart){
  __shared__ alignas(16) unsigned short Kbuf[2][8192];
  __shared__ alignas(16) unsigned short Vbuf[2][8192];
  int bid = blockIdx.x;
  int j = (bid >> 3) & 3;
  int g = (bid & 7) | ((bid >> 5) << 3);
  int s   = g & 3;
  int kvh = (g >> 2) & 7;
  int b   = g >> 5;
  int h   = kvh * 4 + j;

  int tid = threadIdx.x, lane = tid & 63, w = tid >> 6;
  int l16 = lane & 15, lk4 = lane >> 4;
  int lk4x4 = lk4 * 4;

  bf16x8 qf[2][4];
#pragma unroll
  for (int qg = 0; qg < 2; ++qg){
    const unsigned short* qp = Q + (((size_t)(b*NH + h) * QLEN) + w*32 + qg*16 + l16) * HD;
#pragma unroll
    for (int ks = 0; ks < 4; ++ks)
      qf[qg][ks] = *(const bf16x8*)(qp + ks*32 + lk4*8);
  }
  bf16x8 vone;
#pragma unroll
  for (int t = 0; t < 8; ++t) vone[t] = (short)0x3F80;

  f32x4 acc_o[2][8] = {};
  f32x4 acc_l[2] = {};
  float mrun[2] = {-1e30f, -1e30f};

  size_t kvhbase = (size_t)(b*NKVH + kvh) * (KVLEN/64);
  const unsigned short* Ktiles = Kswz + kvhbase * 8192;
  const unsigned short* Vtiles = V2   + kvhbase * 8192;
  size_t qrow0 = (size_t)(b*QLEN + w*32 + l16);

  const int t0 = s * (KVCHUNK/64), t1 = t0 + KVCHUNK/64;
  int srcb0 = (l16 + ((lk4 & 1) << 5)) << 2;
  int srcb1 = srcb0 + 64;

#define STAGE(T, BUF) do { \
    const char* gk_ = (const char*)(Ktiles + (size_t)(T)*8192) + w*4096 + lane*16; \
    const char* gv_ = (const char*)(Vtiles + (size_t)(T)*8192) + w*4096 + lane*16; \
    char* lk_ = (char*)(&Kbuf[BUF][0]) + w*4096; \
    char* lv_ = (char*)(&Vbuf[BUF][0]) + w*4096; \
    _Pragma("unroll") for (int i_ = 0; i_ < 4; ++i_) gl16(gk_ + i_*1024, lk_ + i_*1024); \
    _Pragma("unroll") for (int i_ = 0; i_ < 4; ++i_) gl16(gv_ + i_*1024, lv_ + i_*1024); \
  } while(0)

  STAGE(t0, 0);
  int cur = 0;
  for (int t = t0; t < t1; ++t){
    asm volatile("s_waitcnt vmcnt(0)" ::: "memory");
    asm volatile("s_waitcnt lgkmcnt(0)" ::: "memory");
    __builtin_amdgcn_s_barrier();
    __builtin_amdgcn_sched_barrier(0);
    if (t + 1 < t1) STAGE(t + 1, cur ^ 1);

    unsigned long long wrd[2];
    wrd[0] = bits[qrow0*64 + (size_t)t];
    wrd[1] = bits[(qrow0 + 16)*64 + (size_t)t];

    const char* Kc = (const char*)&Kbuf[cur][0];
    const char* Vc = (const char*)&Vbuf[cur][0];

    f32x4 sacc[2][4] = {};
#pragma unroll
    for (int nf = 0; nf < 4; ++nf){
      int krow = nf*16 + l16;
#pragma unroll
      for (int ks = 0; ks < 4; ++ks){
        unsigned byteoff = ((unsigned)krow*256u + (unsigned)(ks*32 + lk4*8)*2u) ^ (((unsigned)krow & 7u) << 4);
        bf16x8 kf = *(const bf16x8*)(Kc + byteoff);
        sacc[0][nf] = __builtin_amdgcn_mfma_f32_16x16x32_bf16(kf, qf[0][ks], sacc[0][nf], 0, 0, 0);
        sacc[1][nf] = __builtin_amdgcn_mfma_f32_16x16x32_bf16(kf, qf[1][ks], sacc[1][nf], 0, 0, 0);
      }
    }

    unsigned P32[2][8];
#pragma unroll
    for (int qg = 0; qg < 2; ++qg){
      float pp[4][4];
      float pm = -1e30f;
#pragma unroll
      for (int nf = 0; nf < 4; ++nf)
#pragma unroll
        for (int r = 0; r < 4; ++r){
          bool mk = (wrd[qg] >> (nf*16 + lk4x4 + r)) & 1ull;
          float sv = mk ? -20000.f : sacc[qg][nf][r];
          pp[nf][r] = sv;
          pm = fmaxf(pm, sv);
        }
      pm = fmaxf(pm, __shfl_xor(pm, 16, 64));
      pm = fmaxf(pm, __shfl_xor(pm, 32, 64));
      if (__any(pm > mrun[qg])){
        float mnew = fmaxf(mrun[qg], pm);
        float corr = exp2f(mrun[qg] - mnew);
        mrun[qg] = mnew;
#pragma unroll
        for (int nf8 = 0; nf8 < 8; ++nf8)
#pragma unroll
          for (int r = 0; r < 4; ++r) acc_o[qg][nf8][r] *= corr;
#pragma unroll
        for (int r = 0; r < 4; ++r) acc_l[qg][r] *= corr;
      }
#pragma unroll
      for (int nf = 0; nf < 4; ++nf){
        float e0 = exp2f(pp[nf][0] - mrun[qg]);
        float e1 = exp2f(pp[nf][1] - mrun[qg]);
        float e2 = exp2f(pp[nf][2] - mrun[qg]);
        float e3 = exp2f(pp[nf][3] - mrun[qg]);
        P32[qg][nf*2]     = pk2bf(e0, e1);
        P32[qg][nf*2 + 1] = pk2bf(e2, e3);
      }
    }

    bf16x8 pf[2][2];
    bool hi = lk4 >= 2;
#pragma unroll
    for (int qg = 0; qg < 2; ++qg)
#pragma unroll
      for (int ks2 = 0; ks2 < 2; ++ks2){
        int a0 = __builtin_amdgcn_ds_bpermute(srcb0, (int)P32[qg][ks2*4 + 0]);
        int b0 = __builtin_amdgcn_ds_bpermute(srcb0, (int)P32[qg][ks2*4 + 2]);
        int a1 = __builtin_amdgcn_ds_bpermute(srcb0, (int)P32[qg][ks2*4 + 1]);
        int b1 = __builtin_amdgcn_ds_bpermute(srcb0, (int)P32[qg][ks2*4 + 3]);
        int a2 = __builtin_amdgcn_ds_bpermute(srcb1, (int)P32[qg][ks2*4 + 0]);
        int b2 = __builtin_amdgcn_ds_bpermute(srcb1, (int)P32[qg][ks2*4 + 2]);
        int a3 = __builtin_amdgcn_ds_bpermute(srcb1, (int)P32[qg][ks2*4 + 1]);
        int b3 = __builtin_amdgcn_ds_bpermute(srcb1, (int)P32[qg][ks2*4 + 3]);
        i32x4 wv = { hi ? b0 : a0, hi ? b1 : a1, hi ? b2 : a2, hi ? b3 : a3 };
        pf[qg][ks2] = __builtin_bit_cast(bf16x8, wv);
      }

#pragma unroll
    for (int nf8 = 0; nf8 < 8; ++nf8)
#pragma unroll
      for (int ks2 = 0; ks2 < 2; ++ks2){
        unsigned base = (unsigned)(nf8*2 + ks2)*1024u + (unsigned)lane*16u;
        unsigned byteoff = VSWZ(base);
        bf16x8 vf = *(const bf16x8*)(Vc + byteoff);
        acc_o[0][nf8] = __builtin_amdgcn_mfma_f32_16x16x32_bf16(vf, pf[0][ks2], acc_o[0][nf8], 0, 0, 0);
        acc_o[1][nf8] = __builtin_amdgcn_mfma_f32_16x16x32_bf16(vf, pf[1][ks2], acc_o[1][nf8], 0, 0, 0);
      }
#pragma unroll
    for (int qg = 0; qg < 2; ++qg)
#pragma unroll
      for (int ks2 = 0; ks2 < 2; ++ks2)
        acc_l[qg] = __builtin_amdgcn_mfma_f32_16x16x32_bf16(vone, pf[qg][ks2], acc_l[qg], 0, 0, 0);

    cur ^= 1;
  }
#undef STAGE

  size_t rowbase = ((size_t)(s*4 + b) * NH + h) * QLEN + w*32 + l16;
#pragma unroll
  for (int qg = 0; qg < 2; ++qg){
    size_t row = rowbase + qg*16;
#pragma unroll
    for (int nf8 = 0; nf8 < 8; ++nf8){
      s16x4 o;
#pragma unroll
      for (int r = 0; r < 4; ++r) o[r] = (short)f2bf(acc_o[qg][nf8][r]);
      *(s16x4*)&Opart[row * HD + nf8*16 + lk4x4] = o;
    }
    if (lk4 == 0){
      Mpart[row] = mrun[qg];
      Lpart[row] = acc_l[qg][0];
    }
  }
}

// ---------------- combine: merge NSPLIT bf16 partials -> bf16 A-image for GEMM2 ----------------
__global__ __launch_bounds__(256) void combine_kernel(const unsigned short* __restrict__ Opart,
                                                      const float* __restrict__ Mpart,
                                                      const float* __restrict__ Lpart,
                                                      unsigned short* __restrict__ A2img){
  int idx = blockIdx.x * 256 + threadIdx.x;
  int d4 = idx & 31;
  int row = idx >> 5;
  const int RS = 4 * NH * QLEN;
  float m[NSPLIT];
  float M = -1e30f;
#pragma unroll
  for (int s = 0; s < NSPLIT; ++s){
    m[s] = Mpart[(size_t)s*RS + row];
    M = fmaxf(M, m[s]);
  }
  float L = 0.f;
  f32x4 num = {};
#pragma unroll
  for (int s = 0; s < NSPLIT; ++s){
    float wsc = exp2f(m[s] - M);
    L += wsc * Lpart[(size_t)s*RS + row];
    s16x4 o = *(const s16x4*)&Opart[((size_t)s*RS + row) * HD + d4*4];
#pragma unroll
    for (int t = 0; t < 4; ++t) num[t] += wsc * bf2f((unsigned short)o[t]);
  }
  int ql = row & 127, h = (row >> 7) & 31, b = row >> 12;
  int bm = b*2 + (ql >> 6), mm = ql & 63;
  int kt = h*2 + (d4 >> 4), kl = (d4*4) & 63;
  s16x4 res;
#pragma unroll
  for (int t = 0; t < 4; ++t) res[t] = (short)f2bf(num[t] / L);
  char* tile = (char*)A2img + (size_t)(bm*64 + kt) * 8192;
  unsigned off = ((unsigned)(mm*128 + kl*2)) ^ (((unsigned)mm & 7u) << 4);
  *(s16x4*)(tile + off) = res;
}

// ---------------- launch ----------------
extern "C" void kernel_launch(void* const* d_in, const int* in_sizes, int n_in,
                              void* d_out, int out_size, void* d_ws, size_t ws_size,
                              hipStream_t stream){
  (void)in_sizes; (void)n_in; (void)out_size; (void)ws_size;
  const float* hidden = (const float*)d_in[0];
  const float* kst    = (const float*)d_in[1];
  const float* vst    = (const float*)d_in[2];
  const float* wq     = (const float*)d_in[3];
  const float* wo     = (const float*)d_in[4];
  const void*  pos    = d_in[5];
  const void*  mask   = d_in[6];
  float* out = (float*)d_out;

  char* ws = (char*)d_ws;
  unsigned short* Kswz  = (unsigned short*)ws;                   // 32 MiB
  unsigned short* V2    = (unsigned short*)(ws + (32u << 20));   // 32 MiB
  unsigned short* WoImg = (unsigned short*)(ws + (64u << 20));   // 32 MiB
  unsigned short* WqImg = (unsigned short*)(ws + (96u << 20));   // 32 MiB (dead after GEMM1)
  unsigned short* Opart = (unsigned short*)(ws + (96u << 20));   // 16 MiB overlay on WqImg
  unsigned short* A1img = (unsigned short*)(ws + (128u << 20));  // 4 MiB
  unsigned short* qbf   = (unsigned short*)(ws + (132u << 20));  // 4 MiB
  unsigned short* A2img = (unsigned short*)(ws + (136u << 20));  // 4 MiB
  float* Mpart = (float*)(ws + (140u << 20));                    // 256 KiB
  float* Lpart = (float*)(ws + (140u << 20) + (256u << 10));     // 256 KiB
  unsigned long long* bits = (unsigned long long*)(ws + (140u << 20) + (512u << 10)); // 256 KiB
  float* costab = (float*)(ws + (141u << 20));
  float* sintab = costab + 256;

  prep_kernel<<<1, 256, 0, stream>>>((const int*)pos, costab, sintab);
  prepall_kernel<<<12800, 256, 0, stream>>>(kst, vst, wq, wo, hidden, mask,
                                            costab, sintab,
                                            Kswz, V2, WqImg, WoImg, A1img, bits);
  gemm_kernel<1><<<512, 256, 0, stream>>>(A1img, WqImg, qbf);
  attn_kernel<<<512, 256, 0, stream>>>(qbf, Kswz, V2, bits, Opart, Mpart, Lpart);
  combine_kernel<<<2048, 256, 0, stream>>>(Opart, Mpart, Lpart, A2img);
  gemm_kernel<0><<<512, 256, 0, stream>>>(A2img, WoImg, out);
}

// Round 19
// 205.384 us; speedup vs baseline: 1.1971x; 1.0638x over previous
//
#include <hip/hip_runtime.h>
#include <math.h>

typedef __attribute__((ext_vector_type(8))) short bf16x8;
typedef __attribute__((ext_vector_type(4))) float f32x4;
typedef __attribute__((ext_vector_type(4))) short s16x4;
typedef __attribute__((ext_vector_type(4))) int i32x4;

__device__ inline unsigned short f2bf(float x){
  unsigned u = __builtin_bit_cast(unsigned, x);
  u = (u + 0x7FFFu + ((u >> 16) & 1u)) >> 16;
  return (unsigned short)u;
}
__device__ inline float bf2f(unsigned short v){
  return __builtin_bit_cast(float, (unsigned)v << 16);
}
__device__ inline unsigned pk2bf(float lo, float hi){
  return (unsigned)f2bf(lo) | ((unsigned)f2bf(hi) << 16);
}

__device__ inline void gl16(const void* g, void* l){
  __builtin_amdgcn_global_load_lds(
      (const __attribute__((address_space(1))) unsigned int*)g,
      (__attribute__((address_space(3))) unsigned int*)l, 16, 0, 0);
}

#define KVLEN 4096
#define QLEN  128
#define NH    32
#define NKVH  8
#define HD    128
#define HIDD  4096
#define NSPLIT 4
#define KVCHUNK (KVLEN / NSPLIT)

#define WSWZ(n) ((((unsigned)(n) & 7u) ^ (((unsigned)(n) >> 3) & 7u)) << 4)
#define VSWZ(byte) ((byte) ^ ((((byte) >> 11) & 7u) << 4))

// ---------------- prep: per-batch RoPE tables (double precision, exact) ----------------
__global__ void prep_kernel(const int* __restrict__ pos32,
                            float* __restrict__ costab,
                            float* __restrict__ sintab){
  int tid = threadIdx.x;
  int b = tid >> 6, j = tid & 63;
  bool pos64 = (pos32[2*4095 + 1] == 0);
  long long mpos;
  if (pos64) mpos = ((const long long*)pos32)[(size_t)b*KVLEN + KVLEN - 1];
  else       mpos = (long long)pos32[(size_t)b*KVLEN + KVLEN - 1];
  double inv = pow(10000.0, -((double)j) / 64.0);
  double ang = (double)mpos * inv;
  costab[b*64 + j] = (float)cos(ang);
  sintab[b*64 + j] = (float)sin(ang);
}

// ---------------- prepall: maskpack + kvprep(+RoPE on K) + wprep + A-tiles ----------------
// nt LOADS only on W (single-read stream, never touched downstream).
// K read twice in-block (dp partner) -> normal loads; image stores normal (r17 lesson).
__global__ __launch_bounds__(256) void prepall_kernel(
    const float* __restrict__ Kg, const float* __restrict__ Vg,
    const float* __restrict__ Wq, const float* __restrict__ Wo,
    const float* __restrict__ hidden, const void* __restrict__ mask,
    const float* __restrict__ costab, const float* __restrict__ sintab,
    unsigned short* __restrict__ Kswz, unsigned short* __restrict__ V2,
    unsigned short* __restrict__ WqImg, unsigned short* __restrict__ WoImg,
    unsigned short* __restrict__ A1img,
    unsigned long long* __restrict__ bits){
  __shared__ alignas(16) char tl[16384];
  int bid = blockIdx.x, tid = threadIdx.x;

  if (bid < 2048){
    const unsigned int* m32 = (const unsigned int*)mask;
    unsigned long long det = __ballot((m32[tid & 63] & 0xFFFFFF00u) != 0);
    bool m8 = (det != 0);
#pragma unroll
    for (int it = 0; it < 4; ++it){
      int idx = bid * 1024 + it * 256 + tid;
      bool v = m8 ? (((const unsigned char*)mask)[idx] != 0)
                  : (((const int*)mask)[idx] != 0);
      unsigned long long bal = __ballot(v);
      if ((tid & 63) == 0) bits[idx >> 6] = bal;
    }

  } else if (bid < 4096){
    // ---- kvprep: t = b*512 + kvh*64 + tile ----
    int t = bid - 2048;
    int b = t >> 9;
    const float* kin = Kg + (size_t)t * 8192;
    const float* vin = Vg + (size_t)t * 8192;
    unsigned short* kout = Kswz + (size_t)t * 8192;
    unsigned short* vout = V2   + (size_t)t * 8192;
#pragma unroll
    for (int i = 0; i < 4; ++i){
      int c = tid + 256*i;
      int r = c >> 4, d0 = (c & 15) * 8;
      int dp = d0 ^ 64;
      bool low = d0 < 64;
      f32x4 x0 = *(const f32x4*)(kin + r*128 + d0);
      f32x4 x1 = *(const f32x4*)(kin + r*128 + d0 + 4);
      f32x4 y0 = *(const f32x4*)(kin + r*128 + dp);
      f32x4 y1 = *(const f32x4*)(kin + r*128 + dp + 4);
      int j0 = d0 & 63;
      bf16x8 s;
#pragma unroll
      for (int tt = 0; tt < 8; ++tt){
        float cc = costab[b*64 + j0 + tt];
        float ss = sintab[b*64 + j0 + tt];
        float x = (tt < 4) ? x0[tt] : x1[tt-4];
        float y = (tt < 4) ? y0[tt] : y1[tt-4];
        float v = low ? (x*cc + y*ss) : (x*cc - y*ss);
        s[tt] = (short)f2bf(v);
      }
      unsigned o = ((unsigned)(r*256 + d0*2)) ^ (((unsigned)r & 7u) << 4);
      *(bf16x8*)(tl + o) = s;
    }
    __syncthreads();
#pragma unroll
    for (int i = 0; i < 4; ++i)
      *(bf16x8*)((char*)kout + tid*16 + i*4096) = *(const bf16x8*)(tl + tid*16 + i*4096);
    __syncthreads();
#pragma unroll
    for (int i = 0; i < 4; ++i){
      int c = tid + 256*i;
      int r = c >> 4, d0 = (c & 15) * 8;
      f32x4 x0 = *(const f32x4*)(vin + r*128 + d0);
      f32x4 x1 = *(const f32x4*)(vin + r*128 + d0 + 4);
      int ks2 = r >> 5, lk4 = (r >> 3) & 3, e = r & 7;
#pragma unroll
      for (int tt = 0; tt < 8; ++tt){
        int d = d0 + tt;
        float v = (tt < 4) ? x0[tt] : x1[tt-4];
        unsigned cc = (unsigned)((((d >> 4)*2 + ks2)*4 + lk4)*16 + (d & 15));
        unsigned byte = cc*16u + (unsigned)e*2u;
        *(unsigned short*)(tl + VSWZ(byte)) = f2bf(v);
      }
    }
    __syncthreads();
#pragma unroll
    for (int i = 0; i < 4; ++i)
      *(bf16x8*)((char*)vout + tid*16 + i*4096) = *(const bf16x8*)(tl + tid*16 + i*4096);

  } else {
    int t = bid - 4096;
    if (t < 8192){
      // B-tiles, bn-fast ordering for DRAM page locality; W loads nontemporal
      const float* W = (t < 4096) ? Wq : Wo;
      unsigned short* img = (t < 4096) ? WqImg : WoImg;
      int tt = t & 4095;
      int kt = tt >> 6, bn = tt & 63;
      char* outB = (char*)img + (size_t)(bn*64 + kt) * 8192;
#pragma unroll
      for (int i = 0; i < 2; ++i){
        int c = tid + 256*i;
        int k = c >> 3, n0 = (c & 7) * 8;
        const float* src = W + (size_t)(kt*64 + k) * HIDD + bn*64 + n0;
        f32x4 x0 = __builtin_nontemporal_load((const f32x4*)src);
        f32x4 x1 = __builtin_nontemporal_load((const f32x4*)(src + 4));
#pragma unroll
        for (int e = 0; e < 8; ++e){
          int n = n0 + e;
          float v = (e < 4) ? x0[e] : x1[e-4];
          unsigned off = ((unsigned)(n*128 + k*2)) ^ WSWZ(n);
          *(unsigned short*)(tl + off) = f2bf(v);
        }
      }
      __syncthreads();
#pragma unroll
      for (int i = 0; i < 2; ++i)
        *(bf16x8*)(outB + tid*16 + i*4096) = *(const bf16x8*)(tl + tid*16 + i*4096);
    } else {
      int ta = t - 8192;                 // [0,512)
      int bm = ta >> 6, kt = ta & 63;
      char* outA = (char*)A1img + (size_t)ta * 8192;
#pragma unroll
      for (int i = 0; i < 2; ++i){
        int c = tid + 256*i;
        int m = c >> 3, kc = c & 7;
        const float* src = hidden + (size_t)(bm*64 + m) * HIDD + kt*64 + kc*8;
        f32x4 x0 = *(const f32x4*)src;
        f32x4 x1 = *(const f32x4*)(src + 4);
        bf16x8 s;
#pragma unroll
        for (int e = 0; e < 4; ++e){ s[e] = (short)f2bf(x0[e]); s[e+4] = (short)f2bf(x1[e]); }
        unsigned off = ((unsigned)(m*128 + kc*16)) ^ (((unsigned)m & 7u) << 4);
        *(bf16x8*)(tl + off) = s;
      }
      __syncthreads();
#pragma unroll
      for (int i = 0; i < 2; ++i)
        *(bf16x8*)(outA + tid*16 + i*4096) = *(const bf16x8*)(tl + tid*16 + i*4096);
    }
  }
}

// ---------------- GEMM: BM=64 BN=64 BK=128, double-buffered (r15-proven) ----------------
template<int EPI>
__global__ __launch_bounds__(256, 2) void gemm_kernel(const unsigned short* __restrict__ Aimg,
                                                      const unsigned short* __restrict__ Bimg,
                                                      void* __restrict__ C_){
  __shared__ alignas(16) char smem[65536];              // 2 x (A 16KB + B 16KB)
  int bid = blockIdx.x;
  int bn = (bid & 7) | ((bid >> 6) << 3);               // same bn -> same XCD
  int bm = (bid >> 3) & 7;
  int tid = threadIdx.x, lane = tid & 63, w = tid >> 6;
  int wm = w >> 1, wn = w & 1;
  int l16 = lane & 15, lk4 = lane >> 4;
  const char* At = (const char*)Aimg + (size_t)(bm*64) * 8192;
  const char* Bt = (const char*)Bimg + (size_t)(bn*64) * 8192;
  f32x4 acc[2][2] = {};

#define GSTAGE(KT2, BUF) do { \
    const char* ga_ = At + (size_t)(KT2)*16384 + w*4096 + lane*16; \
    const char* gb_ = Bt + (size_t)(KT2)*16384 + w*4096 + lane*16; \
    char* la_ = smem + (BUF)*32768 + w*4096; \
    char* lb_ = smem + (BUF)*32768 + 16384 + w*4096; \
    _Pragma("unroll") for (int i_ = 0; i_ < 4; ++i_) gl16(ga_ + i_*1024, la_ + i_*1024); \
    _Pragma("unroll") for (int i_ = 0; i_ < 4; ++i_) gl16(gb_ + i_*1024, lb_ + i_*1024); \
  } while(0)

  GSTAGE(0, 0);

  for (int kt = 0; kt < 32; ++kt){
    asm volatile("s_waitcnt vmcnt(0)" ::: "memory");
    asm volatile("s_waitcnt lgkmcnt(0)" ::: "memory");
    __builtin_amdgcn_s_barrier();
    __builtin_amdgcn_sched_barrier(0);
    if (kt + 1 < 32) GSTAGE(kt + 1, (kt + 1) & 1);
    const char* Ab = smem + (kt & 1)*32768;
    const char* Bb = Ab + 16384;
    bf16x8 af[2][4], bfr[2][4];
#pragma unroll
    for (int i = 0; i < 2; ++i)
#pragma unroll
      for (int ks = 0; ks < 4; ++ks){
        unsigned m = (unsigned)(wm*32 + i*16 + l16);
        unsigned off = (unsigned)(ks >> 1)*8192u +
                       ((m*128u + (unsigned)((ks & 1)*64 + lk4*16)) ^ ((m & 7u) << 4));
        af[i][ks] = *(const bf16x8*)(Ab + off);
      }
#pragma unroll
    for (int j = 0; j < 2; ++j)
#pragma unroll
      for (int ks = 0; ks < 4; ++ks){
        unsigned n = (unsigned)(wn*32 + j*16 + l16);
        unsigned off = (unsigned)(ks >> 1)*8192u +
                       ((n*128u + (unsigned)((ks & 1)*64 + lk4*16)) ^ WSWZ(n));
        bfr[j][ks] = *(const bf16x8*)(Bb + off);
      }
#pragma unroll
    for (int i = 0; i < 2; ++i)
#pragma unroll
      for (int j = 0; j < 2; ++j)
#pragma unroll
        for (int ks = 0; ks < 4; ++ks)
          acc[i][j] = __builtin_amdgcn_mfma_f32_16x16x32_bf16(af[i][ks], bfr[j][ks], acc[i][j], 0, 0, 0);
  }
#undef GSTAGE

  if (EPI == 0){
    float* C = (float*)C_;
#pragma unroll
    for (int i = 0; i < 2; ++i)
#pragma unroll
      for (int j = 0; j < 2; ++j)
#pragma unroll
        for (int r = 0; r < 4; ++r){
          int row = bm*64 + wm*32 + i*16 + lk4*4 + r;
          int col = bn*64 + wn*32 + j*16 + l16;
          C[(size_t)row * HIDD + col] = acc[i][j][r];
        }
  } else {
    unsigned short* Q = (unsigned short*)C_;
    const float scale = 0.08838834764831845f * 1.4426950408889634f;  // 1/sqrt(D) * log2(e)
#pragma unroll
    for (int i = 0; i < 2; ++i)
#pragma unroll
      for (int j = 0; j < 2; ++j)
#pragma unroll
        for (int r = 0; r < 4; ++r){
          int row = bm*64 + wm*32 + i*16 + lk4*4 + r;
          int col = bn*64 + wn*32 + j*16 + l16;
          int b = row >> 7, ql = row & 127;
          int h = col >> 7, d = col & 127;
          Q[(((size_t)(b*NH + h)) * QLEN + ql) * HD + d] = f2bf(acc[i][j][r] * scale);
        }
  }
}

// ---------------- flash attention: 4-wave blocks, 1 head, qg=2, NSPLIT=4, grid 512 ----
__global__ __launch_bounds__(256, 2) void attn_kernel(const unsigned short* __restrict__ Q,
                                                      const unsigned short* __restrict__ Kswz,
                                                      const unsigned short* __restrict__ V2,
                                                      const unsigned long long* __restrict__ bits,
                                                      unsigned short* __restrict__ Opart,
                                                      float* __restrict__ Mpart,
                                                      float* __restrict__ Lpart){
  __shared__ alignas(16) unsigned short Kbuf[2][8192];
  __shared__ alignas(16) unsigned short Vbuf[2][8192];
  int bid = blockIdx.x;
  int j = (bid >> 3) & 3;
  int g = (bid & 7) | ((bid >> 5) << 3);
  int s   = g & 3;
  int kvh = (g >> 2) & 7;
  int b   = g >> 5;
  int h   = kvh * 4 + j;

  int tid = threadIdx.x, lane = tid & 63, w = tid >> 6;
  int l16 = lane & 15, lk4 = lane >> 4;
  int lk4x4 = lk4 * 4;

  bf16x8 qf[2][4];
#pragma unroll
  for (int qg = 0; qg < 2; ++qg){
    const unsigned short* qp = Q + (((size_t)(b*NH + h) * QLEN) + w*32 + qg*16 + l16) * HD;
#pragma unroll
    for (int ks = 0; ks < 4; ++ks)
      qf[qg][ks] = *(const bf16x8*)(qp + ks*32 + lk4*8);
  }
  bf16x8 vone;
#pragma unroll
  for (int t = 0; t < 8; ++t) vone[t] = (short)0x3F80;

  f32x4 acc_o[2][8] = {};
  f32x4 acc_l[2] = {};
  float mrun[2] = {-1e30f, -1e30f};

  size_t kvhbase = (size_t)(b*NKVH + kvh) * (KVLEN/64);
  const unsigned short* Ktiles = Kswz + kvhbase * 8192;
  const unsigned short* Vtiles = V2   + kvhbase * 8192;
  size_t qrow0 = (size_t)(b*QLEN + w*32 + l16);

  const int t0 = s * (KVCHUNK/64), t1 = t0 + KVCHUNK/64;
  int srcb0 = (l16 + ((lk4 & 1) << 5)) << 2;
  int srcb1 = srcb0 + 64;

#define STAGE(T, BUF) do { \
    const char* gk_ = (const char*)(Ktiles + (size_t)(T)*8192) + w*4096 + lane*16; \
    const char* gv_ = (const char*)(Vtiles + (size_t)(T)*8192) + w*4096 + lane*16; \
    char* lk_ = (char*)(&Kbuf[BUF][0]) + w*4096; \
    char* lv_ = (char*)(&Vbuf[BUF][0]) + w*4096; \
    _Pragma("unroll") for (int i_ = 0; i_ < 4; ++i_) gl16(gk_ + i_*1024, lk_ + i_*1024); \
    _Pragma("unroll") for (int i_ = 0; i_ < 4; ++i_) gl16(gv_ + i_*1024, lv_ + i_*1024); \
  } while(0)

  STAGE(t0, 0);
  int cur = 0;
  for (int t = t0; t < t1; ++t){
    asm volatile("s_waitcnt vmcnt(0)" ::: "memory");
    asm volatile("s_waitcnt lgkmcnt(0)" ::: "memory");
    __builtin_amdgcn_s_barrier();
    __builtin_amdgcn_sched_barrier(0);
    if (t + 1 < t1) STAGE(t + 1, cur ^ 1);

    unsigned long long wrd[2];
    wrd[0] = bits[qrow0*64 + (size_t)t];
    wrd[1] = bits[(qrow0 + 16)*64 + (size_t)t];

    const char* Kc = (const char*)&Kbuf[cur][0];
    const char* Vc = (const char*)&Vbuf[cur][0];

    f32x4 sacc[2][4] = {};
#pragma unroll
    for (int nf = 0; nf < 4; ++nf){
      int krow = nf*16 + l16;
#pragma unroll
      for (int ks = 0; ks < 4; ++ks){
        unsigned byteoff = ((unsigned)krow*256u + (unsigned)(ks*32 + lk4*8)*2u) ^ (((unsigned)krow & 7u) << 4);
        bf16x8 kf = *(const bf16x8*)(Kc + byteoff);
        sacc[0][nf] = __builtin_amdgcn_mfma_f32_16x16x32_bf16(kf, qf[0][ks], sacc[0][nf], 0, 0, 0);
        sacc[1][nf] = __builtin_amdgcn_mfma_f32_16x16x32_bf16(kf, qf[1][ks], sacc[1][nf], 0, 0, 0);
      }
    }

    unsigned P32[2][8];
#pragma unroll
    for (int qg = 0; qg < 2; ++qg){
      float pp[4][4];
      float pm = -1e30f;
#pragma unroll
      for (int nf = 0; nf < 4; ++nf)
#pragma unroll
        for (int r = 0; r < 4; ++r){
          bool mk = (wrd[qg] >> (nf*16 + lk4x4 + r)) & 1ull;
          float sv = mk ? -20000.f : sacc[qg][nf][r];
          pp[nf][r] = sv;
          pm = fmaxf(pm, sv);
        }
      pm = fmaxf(pm, __shfl_xor(pm, 16, 64));
      pm = fmaxf(pm, __shfl_xor(pm, 32, 64));
      if (__any(pm > mrun[qg])){
        float mnew = fmaxf(mrun[qg], pm);
        float corr = exp2f(mrun[qg] - mnew);
        mrun[qg] = mnew;
#pragma unroll
        for (int nf8 = 0; nf8 < 8; ++nf8)
#pragma unroll
          for (int r = 0; r < 4; ++r) acc_o[qg][nf8][r] *= corr;
#pragma unroll
        for (int r = 0; r < 4; ++r) acc_l[qg][r] *= corr;
      }
#pragma unroll
      for (int nf = 0; nf < 4; ++nf){
        float e0 = exp2f(pp[nf][0] - mrun[qg]);
        float e1 = exp2f(pp[nf][1] - mrun[qg]);
        float e2 = exp2f(pp[nf][2] - mrun[qg]);
        float e3 = exp2f(pp[nf][3] - mrun[qg]);
        P32[qg][nf*2]     = pk2bf(e0, e1);
        P32[qg][nf*2 + 1] = pk2bf(e2, e3);
      }
    }

    bf16x8 pf[2][2];
    bool hi = lk4 >= 2;
#pragma unroll
    for (int qg = 0; qg < 2; ++qg)
#pragma unroll
      for (int ks2 = 0; ks2 < 2; ++ks2){
        int a0 = __builtin_amdgcn_ds_bpermute(srcb0, (int)P32[qg][ks2*4 + 0]);
        int b0 = __builtin_amdgcn_ds_bpermute(srcb0, (int)P32[qg][ks2*4 + 2]);
        int a1 = __builtin_amdgcn_ds_bpermute(srcb0, (int)P32[qg][ks2*4 + 1]);
        int b1 = __builtin_amdgcn_ds_bpermute(srcb0, (int)P32[qg][ks2*4 + 3]);
        int a2 = __builtin_amdgcn_ds_bpermute(srcb1, (int)P32[qg][ks2*4 + 0]);
        int b2 = __builtin_amdgcn_ds_bpermute(srcb1, (int)P32[qg][ks2*4 + 2]);
        int a3 = __builtin_amdgcn_ds_bpermute(srcb1, (int)P32[qg][ks2*4 + 1]);
        int b3 = __builtin_amdgcn_ds_bpermute(srcb1, (int)P32[qg][ks2*4 + 3]);
        i32x4 wv = { hi ? b0 : a0, hi ? b1 : a1, hi ? b2 : a2, hi ? b3 : a3 };
        pf[qg][ks2] = __builtin_bit_cast(bf16x8, wv);
      }

#pragma unroll
    for (int nf8 = 0; nf8 < 8; ++nf8)
#pragma unroll
      for (int ks2 = 0; ks2 < 2; ++ks2){
        unsigned base = (unsigned)(nf8*2 + ks2)*1024u + (unsigned)lane*16u;
        unsigned byteoff = VSWZ(base);
        bf16x8 vf = *(const bf16x8*)(Vc + byteoff);
        acc_o[0][nf8] = __builtin_amdgcn_mfma_f32_16x16x32_bf16(vf, pf[0][ks2], acc_o[0][nf8], 0, 0, 0);
        acc_o[1][nf8] = __builtin_amdgcn_mfma_f32_16x16x32_bf16(vf, pf[1][ks2], acc_o[1][nf8], 0, 0, 0);
      }
#pragma unroll
    for (int qg = 0; qg < 2; ++qg)
#pragma unroll
      for (int ks2 = 0; ks2 < 2; ++ks2)
        acc_l[qg] = __builtin_amdgcn_mfma_f32_16x16x32_bf16(vone, pf[qg][ks2], acc_l[qg], 0, 0, 0);

    cur ^= 1;
  }
#undef STAGE

  size_t rowbase = ((size_t)(s*4 + b) * NH + h) * QLEN + w*32 + l16;
#pragma unroll
  for (int qg = 0; qg < 2; ++qg){
    size_t row = rowbase + qg*16;
#pragma unroll
    for (int nf8 = 0; nf8 < 8; ++nf8){
      s16x4 o;
#pragma unroll
      for (int r = 0; r < 4; ++r) o[r] = (short)f2bf(acc_o[qg][nf8][r]);
      *(s16x4*)&Opart[row * HD + nf8*16 + lk4x4] = o;
    }
    if (lk4 == 0){
      Mpart[row] = mrun[qg];
      Lpart[row] = acc_l[qg][0];
    }
  }
}

// ---------------- combine: merge NSPLIT bf16 partials -> bf16 A-image for GEMM2 ----------------
__global__ __launch_bounds__(256) void combine_kernel(const unsigned short* __restrict__ Opart,
                                                      const float* __restrict__ Mpart,
                                                      const float* __restrict__ Lpart,
                                                      unsigned short* __restrict__ A2img){
  int idx = blockIdx.x * 256 + threadIdx.x;
  int d4 = idx & 31;
  int row = idx >> 5;
  const int RS = 4 * NH * QLEN;
  float m[NSPLIT];
  float M = -1e30f;
#pragma unroll
  for (int s = 0; s < NSPLIT; ++s){
    m[s] = Mpart[(size_t)s*RS + row];
    M = fmaxf(M, m[s]);
  }
  float L = 0.f;
  f32x4 num = {};
#pragma unroll
  for (int s = 0; s < NSPLIT; ++s){
    float wsc = exp2f(m[s] - M);
    L += wsc * Lpart[(size_t)s*RS + row];
    s16x4 o = *(const s16x4*)&Opart[((size_t)s*RS + row) * HD + d4*4];
#pragma unroll
    for (int t = 0; t < 4; ++t) num[t] += wsc * bf2f((unsigned short)o[t]);
  }
  int ql = row & 127, h = (row >> 7) & 31, b = row >> 12;
  int bm = b*2 + (ql >> 6), mm = ql & 63;
  int kt = h*2 + (d4 >> 4), kl = (d4*4) & 63;
  s16x4 res;
#pragma unroll
  for (int t = 0; t < 4; ++t) res[t] = (short)f2bf(num[t] / L);
  char* tile = (char*)A2img + (size_t)(bm*64 + kt) * 8192;
  unsigned off = ((unsigned)(mm*128 + kl*2)) ^ (((unsigned)mm & 7u) << 4);
  *(s16x4*)(tile + off) = res;
}

// ---------------- launch ----------------
extern "C" void kernel_launch(void* const* d_in, const int* in_sizes, int n_in,
                              void* d_out, int out_size, void* d_ws, size_t ws_size,
                              hipStream_t stream){
  (void)in_sizes; (void)n_in; (void)out_size; (void)ws_size;
  const float* hidden = (const float*)d_in[0];
  const float* kst    = (const float*)d_in[1];
  const float* vst    = (const float*)d_in[2];
  const float* wq     = (const float*)d_in[3];
  const float* wo     = (const float*)d_in[4];
  const void*  pos    = d_in[5];
  const void*  mask   = d_in[6];
  float* out = (float*)d_out;

  char* ws = (char*)d_ws;
  unsigned short* Kswz  = (unsigned short*)ws;                   // 32 MiB
  unsigned short* V2    = (unsigned short*)(ws + (32u << 20));   // 32 MiB
  unsigned short* WoImg = (unsigned short*)(ws + (64u << 20));   // 32 MiB
  unsigned short* WqImg = (unsigned short*)(ws + (96u << 20));   // 32 MiB (dead after GEMM1)
  unsigned short* Opart = (unsigned short*)(ws + (96u << 20));   // 16 MiB overlay on WqImg
  unsigned short* A1img = (unsigned short*)(ws + (128u << 20));  // 4 MiB
  unsigned short* qbf   = (unsigned short*)(ws + (132u << 20));  // 4 MiB
  unsigned short* A2img = (unsigned short*)(ws + (136u << 20));  // 4 MiB
  float* Mpart = (float*)(ws + (140u << 20));                    // 256 KiB
  float* Lpart = (float*)(ws + (140u << 20) + (256u << 10));     // 256 KiB
  unsigned long long* bits = (unsigned long long*)(ws + (140u << 20) + (512u << 10)); // 256 KiB
  float* costab = (float*)(ws + (141u << 20));
  float* sintab = costab + 256;

  prep_kernel<<<1, 256, 0, stream>>>((const int*)pos, costab, sintab);
  prepall_kernel<<<12800, 256, 0, stream>>>(kst, vst, wq, wo, hidden, mask,
                                            costab, sintab,
                                            Kswz, V2, WqImg, WoImg, A1img, bits);
  gemm_kernel<1><<<512, 256, 0, stream>>>(A1img, WqImg, qbf);
  attn_kernel<<<512, 256, 0, stream>>>(qbf, Kswz, V2, bits, Opart, Mpart, Lpart);
  combine_kernel<<<2048, 256, 0, stream>>>(Opart, Mpart, Lpart, A2img);
  gemm_kernel<0><<<512, 256, 0, stream>>>(A2img, WoImg, out);
}